// Round 2
// baseline (542.160 us; speedup 1.0000x reference)
//
#include <hip/hip_runtime.h>
#include <math.h>

// Problem constants (reference: B,T,D = 128,2048,256; LAMDA=0.5)
#define BB 128
#define TT 2048
#define DD 256
#define SPLIT 8
#define ROWS_PER_BLOCK (TT / SPLIT)           // 256
#define WAVES 4
#define ROWS_PER_WAVE (ROWS_PER_BLOCK / WAVES) // 64

// Workspace layout (in floats)
#define WS_MIDS 0                               // B*D
#define WS_P1ACC (WS_MIDS + BB * DD)            // B*SPLIT*D
#define WS_P1SUM (WS_P1ACC + BB * SPLIT * DD)   // B*SPLIT
#define WS_P2ACC_SS (WS_P1SUM + BB * SPLIT)     // B*SPLIT*D
#define WS_P2ACC_SA (WS_P2ACC_SS + BB * SPLIT * DD) // B*SPLIT*D
#define WS_P2SUM_SS (WS_P2ACC_SA + BB * SPLIT * DD) // B*SPLIT
#define WS_P2SUM_SA (WS_P2SUM_SS + BB * SPLIT)      // B*SPLIT
// total = 822272 floats = ~3.3 MB

__device__ __forceinline__ float dot4(const float4& a, const float4& b) {
    return a.x * b.x + a.y * b.y + a.z * b.z + a.w * b.w;
}

// Overflow-safe tanh: tanh(x) = sign(x) * (1 - e^{-2|x|}) / (1 + e^{-2|x|})
__device__ __forceinline__ float tanh_fast(float x) {
    float ax = fabsf(x);
    float t = __expf(-2.0f * ax);     // in (0,1], never overflows
    float th = (1.0f - t) / (1.0f + t);
    return copysignf(th, x);
}

// Sum across a 16-lane group using pure-VALU DPP stages (no DS pipe):
// xor1 (quad_perm [1,0,3,2]=0xB1), xor2 (quad_perm [2,3,0,1]=0x4E),
// xor4 (row_half_mirror=0x141, valid: quads already uniform),
// xor8 (row_mirror=0x140, valid: 8-groups already uniform).
__device__ __forceinline__ float red16(float v) {
    int t;
    t = __builtin_amdgcn_update_dpp(0, __float_as_int(v), 0xB1, 0xF, 0xF, true);
    v += __int_as_float(t);
    t = __builtin_amdgcn_update_dpp(0, __float_as_int(v), 0x4E, 0xF, 0xF, true);
    v += __int_as_float(t);
    t = __builtin_amdgcn_update_dpp(0, __float_as_int(v), 0x141, 0xF, 0xF, true);
    v += __int_as_float(t);
    t = __builtin_amdgcn_update_dpp(0, __float_as_int(v), 0x140, 0xF, 0xF, true);
    v += __int_as_float(t);
    return v;
}

// Epilogue-only: sum across the 4 groups of a wave (values uniform in-group).
__device__ __forceinline__ float xmerge(float v) {
    v += __shfl_xor(v, 16, 64);
    v += __shfl_xor(v, 32, 64);
    return v;
}
__device__ __forceinline__ void merge4(float4& a) {
    a.x = xmerge(a.x); a.y = xmerge(a.y);
    a.z = xmerge(a.z); a.w = xmerge(a.w);
}
__device__ __forceinline__ void fma4(float4& a, float s, const float4& v) {
    a.x = fmaf(s, v.x, a.x); a.y = fmaf(s, v.y, a.y);
    a.z = fmaf(s, v.z, a.z); a.w = fmaf(s, v.w, a.w);
}

// K0: mids[b,i] = sum_j aspect[b,j] * W_mul[i,j]   (aspect @ W_mul.T)
__global__ __launch_bounds__(DD) void mids_kernel(
    const float* __restrict__ aspect, const float* __restrict__ W,
    float* __restrict__ ws)
{
    const int b = blockIdx.x;
    const int i = threadIdx.x;
    __shared__ float a[DD];
    a[i] = aspect[b * DD + i];
    __syncthreads();
    const float4* wrow = (const float4*)(W + (size_t)i * DD);
    float acc = 0.f;
    #pragma unroll 8
    for (int j4 = 0; j4 < DD / 4; ++j4) {
        float4 w4 = wrow[j4];
        acc += a[4 * j4 + 0] * w4.x + a[4 * j4 + 1] * w4.y +
               a[4 * j4 + 2] * w4.z + a[4 * j4 + 3] * w4.w;
    }
    ws[WS_MIDS + b * DD + i] = acc;
}

// K_main: grid (SPLIT, B).  Each block does BOTH passes over its row slab
// (uniform work -> no z-imbalance tail):
//   phase A: multiplicative attention partials over aspect_memory
//   phase S: two additive heads over sentiment_memory
// Layout: 16-lane group g = lane>>4 owns one row per iteration (4 rows/wave/
// iter); lane sub owns columns {j*64 + sub*4 .. +3} for j=0..3, so load
// instruction j reads a CONTIGUOUS 256 B per group (8 cache lines per wave
// instr -- the R0 layout sub*16..+15 fragmented every load into ~32 lines,
// which was the latency wall: HBM 21%, VALU 9%, nothing saturated).
// Next row-slab is prefetched into registers (1-deep) to hide HBM latency.
// Score reduction is a 4-stage DPP tree (no DS pipe in the hot loop).
// No max-subtraction needed (scores bounded; softmax shift-invariant).
__global__ __launch_bounds__(256) void pass_kernel(
    const float* __restrict__ smem_g, const float* __restrict__ amem_g,
    const float* __restrict__ mask, const float* __restrict__ w_ss,
    const float* __restrict__ w_sa, const float* __restrict__ b_mul,
    float* __restrict__ ws)
{
    const int s = blockIdx.x;
    const int b = blockIdx.y;
    const int tid = threadIdx.x;
    const int wave = tid >> 6;
    const int lane = tid & 63;
    const int g = lane >> 4;      // group: which row of the 4-row slab
    const int sub = lane & 15;    // strided column ownership (see above)
    const int t0w = s * ROWS_PER_BLOCK + wave * ROWS_PER_WAVE;

    __shared__ __align__(16) float lds_acc[2 * WAVES * DD]; // 8 KB
    __shared__ float lds_sum[2 * WAVES];

    // ---------------- phase A: aspect (multiplicative) ----------------
    {
        const float4* mp = (const float4*)(ws + WS_MIDS + b * DD);
        const float4 m0 = mp[0 * 16 + sub], m1 = mp[1 * 16 + sub],
                     m2 = mp[2 * 16 + sub], m3 = mp[3 * 16 + sub];
        const float bm = b_mul[0];
        const float* base = amem_g + ((size_t)b * TT + t0w + g) * DD + sub * 4;
        float4 a0 = make_float4(0.f,0.f,0.f,0.f), a1 = a0, a2 = a0, a3 = a0;
        float lsum = 0.f;
        float4 v0 = *(const float4*)(base + 0);
        float4 v1 = *(const float4*)(base + 64);
        float4 v2 = *(const float4*)(base + 128);
        float4 v3 = *(const float4*)(base + 192);
        for (int r = 0; r < ROWS_PER_WAVE; r += 4) {
            // prefetch next slab (last iter re-loads same addrs: L1 hit, no branch)
            const int rn = (r + 4 < ROWS_PER_WAVE) ? (r + 4) : r;
            const float* nb = base + (size_t)rn * DD;
            float4 n0 = *(const float4*)(nb + 0);
            float4 n1 = *(const float4*)(nb + 64);
            float4 n2 = *(const float4*)(nb + 128);
            float4 n3 = *(const float4*)(nb + 192);
            float pd = (dot4(v0, m0) + dot4(v1, m1)) +
                       (dot4(v2, m2) + dot4(v3, m3));
            float d = red16(pd);                 // full row dot, all 16 lanes
            float e = __expf(tanh_fast(d + bm));
            lsum += e;
            fma4(a0, e, v0); fma4(a1, e, v1);
            fma4(a2, e, v2); fma4(a3, e, v3);
            v0 = n0; v1 = n1; v2 = n2; v3 = n3;
        }
        lsum = xmerge(lsum);
        merge4(a0); merge4(a1); merge4(a2); merge4(a3);
        if (g == 0) {
            float4* dst = (float4*)(lds_acc + wave * DD);
            dst[0 * 16 + sub] = a0; dst[1 * 16 + sub] = a1;
            dst[2 * 16 + sub] = a2; dst[3 * 16 + sub] = a3;
        }
        if (lane == 0) lds_sum[wave] = lsum;
        __syncthreads();
        float tot = lds_acc[0 * DD + tid] + lds_acc[1 * DD + tid] +
                    lds_acc[2 * DD + tid] + lds_acc[3 * DD + tid];
        ws[WS_P1ACC + (size_t)(b * SPLIT + s) * DD + tid] = tot;
        if (tid == 0)
            ws[WS_P1SUM + b * SPLIT + s] =
                lds_sum[0] + lds_sum[1] + lds_sum[2] + lds_sum[3];
    }

    // ---------------- phase S: sentiment (two additive heads) ----------------
    {
        const float4* wsp = (const float4*)w_ss;
        const float4* wap = (const float4*)w_sa;
        const float4 ws0 = wsp[0 * 16 + sub], ws1 = wsp[1 * 16 + sub],
                     ws2 = wsp[2 * 16 + sub], ws3 = wsp[3 * 16 + sub];
        const float4 wa0 = wap[0 * 16 + sub], wa1 = wap[1 * 16 + sub],
                     wa2 = wap[2 * 16 + sub], wa3 = wap[3 * 16 + sub];
        const float* base = smem_g + ((size_t)b * TT + t0w + g) * DD + sub * 4;
        const float* mrow = mask + (size_t)b * TT + t0w + g;
        float4 s0 = make_float4(0.f,0.f,0.f,0.f), s1 = s0, s2 = s0, s3 = s0;
        float4 q0 = s0, q1 = s0, q2 = s0, q3 = s0;
        float lss = 0.f, lsa = 0.f;
        float4 v0 = *(const float4*)(base + 0);
        float4 v1 = *(const float4*)(base + 64);
        float4 v2 = *(const float4*)(base + 128);
        float4 v3 = *(const float4*)(base + 192);
        for (int r = 0; r < ROWS_PER_WAVE; r += 4) {
            const int rn = (r + 4 < ROWS_PER_WAVE) ? (r + 4) : r;
            const float* nb = base + (size_t)rn * DD;
            float4 n0 = *(const float4*)(nb + 0);
            float4 n1 = *(const float4*)(nb + 64);
            float4 n2 = *(const float4*)(nb + 128);
            float4 n3 = *(const float4*)(nb + 192);
            float m = mrow[r];
            float pds = (dot4(v0, ws0) + dot4(v1, ws1)) +
                        (dot4(v2, ws2) + dot4(v3, ws3));
            float pda = (dot4(v0, wa0) + dot4(v1, wa1)) +
                        (dot4(v2, wa2) + dot4(v3, wa3));
            float dss = red16(pds);
            float dsa = red16(pda);
            float ess = __expf(dss) * m;
            float esa = __expf(dsa) * m;
            lss += ess;
            lsa += esa;
            fma4(s0, ess, v0); fma4(s1, ess, v1);
            fma4(s2, ess, v2); fma4(s3, ess, v3);
            fma4(q0, esa, v0); fma4(q1, esa, v1);
            fma4(q2, esa, v2); fma4(q3, esa, v3);
            v0 = n0; v1 = n1; v2 = n2; v3 = n3;
        }
        lss = xmerge(lss);
        lsa = xmerge(lsa);
        merge4(s0); merge4(s1); merge4(s2); merge4(s3);
        merge4(q0); merge4(q1); merge4(q2); merge4(q3);
        __syncthreads();   // phase-A LDS reads fully done before reuse
        if (g == 0) {
            float4* d1 = (float4*)(lds_acc + wave * DD);
            d1[0 * 16 + sub] = s0; d1[1 * 16 + sub] = s1;
            d1[2 * 16 + sub] = s2; d1[3 * 16 + sub] = s3;
            float4* d2 = (float4*)(lds_acc + (WAVES + wave) * DD);
            d2[0 * 16 + sub] = q0; d2[1 * 16 + sub] = q1;
            d2[2 * 16 + sub] = q2; d2[3 * 16 + sub] = q3;
        }
        if (lane == 0) {
            lds_sum[wave] = lss;
            lds_sum[WAVES + wave] = lsa;
        }
        __syncthreads();
        float tot_ss = lds_acc[0 * DD + tid] + lds_acc[1 * DD + tid] +
                       lds_acc[2 * DD + tid] + lds_acc[3 * DD + tid];
        float tot_sa = lds_acc[(WAVES + 0) * DD + tid] + lds_acc[(WAVES + 1) * DD + tid] +
                       lds_acc[(WAVES + 2) * DD + tid] + lds_acc[(WAVES + 3) * DD + tid];
        ws[WS_P2ACC_SS + (size_t)(b * SPLIT + s) * DD + tid] = tot_ss;
        ws[WS_P2ACC_SA + (size_t)(b * SPLIT + s) * DD + tid] = tot_sa;
        if (tid == 0) {
            ws[WS_P2SUM_SS + b * SPLIT + s] =
                lds_sum[0] + lds_sum[1] + lds_sum[2] + lds_sum[3];
            ws[WS_P2SUM_SA + b * SPLIT + s] =
                lds_sum[4] + lds_sum[5] + lds_sum[6] + lds_sum[7];
        }
    }
}

// K_combine: grid (B, 2).  y=0: aspect_out = aspect + new_aspect.
// y=1: sentiment_out = 0.5*acc_ss/l_ss + 0.5*acc_sa/l_sa.
__global__ __launch_bounds__(DD) void combine_kernel(
    const float* __restrict__ aspect, const float* __restrict__ ws,
    float* __restrict__ out)
{
    const int b = blockIdx.x;
    const int d = threadIdx.x;
    if (blockIdx.y == 0) {
        float acc = 0.f, l = 0.f;
        #pragma unroll
        for (int s = 0; s < SPLIT; ++s)
            acc += ws[WS_P1ACC + (size_t)(b * SPLIT + s) * DD + d];
        #pragma unroll
        for (int s = 0; s < SPLIT; ++s)
            l += ws[WS_P1SUM + b * SPLIT + s];
        out[BB * DD + b * DD + d] = aspect[b * DD + d] + acc / l;
    } else {
        float ass = 0.f, asa = 0.f, lss = 0.f, lsa = 0.f;
        #pragma unroll
        for (int s = 0; s < SPLIT; ++s) {
            ass += ws[WS_P2ACC_SS + (size_t)(b * SPLIT + s) * DD + d];
            asa += ws[WS_P2ACC_SA + (size_t)(b * SPLIT + s) * DD + d];
        }
        #pragma unroll
        for (int s = 0; s < SPLIT; ++s) {
            lss += ws[WS_P2SUM_SS + b * SPLIT + s];
            lsa += ws[WS_P2SUM_SA + b * SPLIT + s];
        }
        out[b * DD + d] = 0.5f * (ass / lss) + 0.5f * (asa / lsa);
    }
}

extern "C" void kernel_launch(void* const* d_in, const int* in_sizes, int n_in,
                              void* d_out, int out_size, void* d_ws, size_t ws_size,
                              hipStream_t stream) {
    (void)in_sizes; (void)n_in; (void)out_size; (void)ws_size;
    // d_in order per setup_inputs():
    // 0 sentiment [B,D] (unused: query term is softmax-shift-invariant)
    // 1 aspect [B,D], 2 sentiment_memory [B,T,D], 3 aspect_memory [B,T,D],
    // 4 mask [B,T], 5 W_mul [D,D], 6 b_mul [1],
    // 7 w_ss [2D], 8 b_ss [1] (unused), 9 w_sa [2D], 10 b_sa [1] (unused)
    const float* aspect = (const float*)d_in[1];
    const float* smem   = (const float*)d_in[2];
    const float* amem   = (const float*)d_in[3];
    const float* mask   = (const float*)d_in[4];
    const float* W_mul  = (const float*)d_in[5];
    const float* b_mul  = (const float*)d_in[6];
    const float* w_ss   = (const float*)d_in[7];
    const float* w_sa   = (const float*)d_in[9];
    float* out = (float*)d_out;
    float* ws  = (float*)d_ws;

    mids_kernel<<<BB, DD, 0, stream>>>(aspect, W_mul, ws);
    pass_kernel<<<dim3(SPLIT, BB), 256, 0, stream>>>(
        smem, amem, mask, w_ss, w_sa, b_mul, ws);
    combine_kernel<<<dim3(BB, 2), DD, 0, stream>>>(aspect, ws, out);
}

// Round 3
// 508.603 us; speedup vs baseline: 1.0660x; 1.0660x over previous
//
#include <hip/hip_runtime.h>
#include <math.h>

// Problem constants (reference: B,T,D = 128,2048,256; LAMDA=0.5)
#define BB 128
#define TT 2048
#define DD 256
#define SPLIT 8
#define ROWS_PER_BLOCK (TT / SPLIT)           // 256
#define WAVES 4
#define ROWS_PER_WAVE (ROWS_PER_BLOCK / WAVES) // 64

// Workspace layout (in floats)
#define WS_MIDS 0                               // B*D
#define WS_P1ACC (WS_MIDS + BB * DD)            // B*SPLIT*D
#define WS_P1SUM (WS_P1ACC + BB * SPLIT * DD)   // B*SPLIT
#define WS_P2ACC_SS (WS_P1SUM + BB * SPLIT)     // B*SPLIT*D
#define WS_P2ACC_SA (WS_P2ACC_SS + BB * SPLIT * DD) // B*SPLIT*D
#define WS_P2SUM_SS (WS_P2ACC_SA + BB * SPLIT * DD) // B*SPLIT
#define WS_P2SUM_SA (WS_P2SUM_SS + BB * SPLIT)      // B*SPLIT
// total = 822272 floats = ~3.3 MB

// ext_vector float4 so __builtin_nontemporal_load accepts it (HIP's float4
// is a struct; the builtin wants scalar/vector types).
typedef float v4f __attribute__((ext_vector_type(4)));

__device__ __forceinline__ v4f ntload4(const float* p) {
    return __builtin_nontemporal_load((const v4f*)p);
}
__device__ __forceinline__ float dot4v(v4f a, v4f b) {
    v4f p = a * b;
    return (p.x + p.y) + (p.z + p.w);
}
__device__ __forceinline__ void fma4v(v4f& a, float s, v4f v) {
    a += s * v;
}

// Overflow-safe tanh: tanh(x) = sign(x) * (1 - e^{-2|x|}) / (1 + e^{-2|x|})
__device__ __forceinline__ float tanh_fast(float x) {
    float ax = fabsf(x);
    float t = __expf(-2.0f * ax);     // in (0,1], never overflows
    float th = (1.0f - t) / (1.0f + t);
    return copysignf(th, x);
}

// Sum across a 16-lane group using pure-VALU DPP stages (no DS pipe):
// xor1 (quad_perm 0xB1), xor2 (quad_perm 0x4E),
// xor4 (row_half_mirror 0x141), xor8 (row_mirror 0x140).
__device__ __forceinline__ float red16(float v) {
    int t;
    t = __builtin_amdgcn_update_dpp(0, __float_as_int(v), 0xB1, 0xF, 0xF, true);
    v += __int_as_float(t);
    t = __builtin_amdgcn_update_dpp(0, __float_as_int(v), 0x4E, 0xF, 0xF, true);
    v += __int_as_float(t);
    t = __builtin_amdgcn_update_dpp(0, __float_as_int(v), 0x141, 0xF, 0xF, true);
    v += __int_as_float(t);
    t = __builtin_amdgcn_update_dpp(0, __float_as_int(v), 0x140, 0xF, 0xF, true);
    v += __int_as_float(t);
    return v;
}

// Epilogue-only: sum across the 4 groups of a wave (values uniform in-group).
__device__ __forceinline__ float xmerge(float v) {
    v += __shfl_xor(v, 16, 64);
    v += __shfl_xor(v, 32, 64);
    return v;
}
__device__ __forceinline__ void merge4(v4f& a) {
    a.x = xmerge(a.x); a.y = xmerge(a.y);
    a.z = xmerge(a.z); a.w = xmerge(a.w);
}

// K0: mids[b,i] = sum_j aspect[b,j] * W_mul[i,j]   (aspect @ W_mul.T)
__global__ __launch_bounds__(DD) void mids_kernel(
    const float* __restrict__ aspect, const float* __restrict__ W,
    float* __restrict__ ws)
{
    const int b = blockIdx.x;
    const int i = threadIdx.x;
    __shared__ float a[DD];
    a[i] = aspect[b * DD + i];
    __syncthreads();
    const float4* wrow = (const float4*)(W + (size_t)i * DD);
    float acc = 0.f;
    #pragma unroll 8
    for (int j4 = 0; j4 < DD / 4; ++j4) {
        float4 w4 = wrow[j4];
        acc += a[4 * j4 + 0] * w4.x + a[4 * j4 + 1] * w4.y +
               a[4 * j4 + 2] * w4.z + a[4 * j4 + 3] * w4.w;
    }
    ws[WS_MIDS + b * DD + i] = acc;
}

// K_main: grid (SPLIT, B).  Each block does BOTH passes over its row slab.
// Structure identical to R1 (16-lane DPP groups, coalesced 256 B/group loads,
// 1-deep register prefetch).  ONE change this round: the two big memory
// streams are loaded NONTEMPORAL.  Evidence: 3 structurally different
// kernels all pin at ~165 us with every pipe idle (HBM 21%, VALU 9%,
// occupancy-invariant), FETCH_SIZE = half the touched bytes -> every access
// transits the thrashing 256 MB L3 (working set 512 MB); hypothesis is the
// L3 lookup/insert/evict path is the ~3.3 TB/s aggregate ceiling.  nt loads
// bypass L3 allocation so the stream runs at HBM rate instead.
__global__ __launch_bounds__(256) void pass_kernel(
    const float* __restrict__ smem_g, const float* __restrict__ amem_g,
    const float* __restrict__ mask, const float* __restrict__ w_ss,
    const float* __restrict__ w_sa, const float* __restrict__ b_mul,
    float* __restrict__ ws)
{
    const int s = blockIdx.x;
    const int b = blockIdx.y;
    const int tid = threadIdx.x;
    const int wave = tid >> 6;
    const int lane = tid & 63;
    const int g = lane >> 4;      // group: which row of the 4-row slab
    const int sub = lane & 15;    // strided column ownership
    const int t0w = s * ROWS_PER_BLOCK + wave * ROWS_PER_WAVE;

    __shared__ __align__(16) float lds_acc[2 * WAVES * DD]; // 8 KB
    __shared__ float lds_sum[2 * WAVES];

    // ---------------- phase A: aspect (multiplicative) ----------------
    {
        const v4f* mp = (const v4f*)(ws + WS_MIDS + b * DD);
        const v4f m0 = mp[0 * 16 + sub], m1 = mp[1 * 16 + sub],
                  m2 = mp[2 * 16 + sub], m3 = mp[3 * 16 + sub];
        const float bm = b_mul[0];
        const float* base = amem_g + ((size_t)b * TT + t0w + g) * DD + sub * 4;
        v4f a0 = (v4f)(0.f), a1 = a0, a2 = a0, a3 = a0;
        float lsum = 0.f;
        v4f v0 = ntload4(base + 0);
        v4f v1 = ntload4(base + 64);
        v4f v2 = ntload4(base + 128);
        v4f v3 = ntload4(base + 192);
        for (int r = 0; r < ROWS_PER_WAVE; r += 4) {
            // prefetch next slab (last iter re-loads same addrs, no branch)
            const int rn = (r + 4 < ROWS_PER_WAVE) ? (r + 4) : r;
            const float* nb = base + (size_t)rn * DD;
            v4f n0 = ntload4(nb + 0);
            v4f n1 = ntload4(nb + 64);
            v4f n2 = ntload4(nb + 128);
            v4f n3 = ntload4(nb + 192);
            float pd = (dot4v(v0, m0) + dot4v(v1, m1)) +
                       (dot4v(v2, m2) + dot4v(v3, m3));
            float d = red16(pd);                 // full row dot, all 16 lanes
            float e = __expf(tanh_fast(d + bm));
            lsum += e;
            fma4v(a0, e, v0); fma4v(a1, e, v1);
            fma4v(a2, e, v2); fma4v(a3, e, v3);
            v0 = n0; v1 = n1; v2 = n2; v3 = n3;
        }
        lsum = xmerge(lsum);
        merge4(a0); merge4(a1); merge4(a2); merge4(a3);
        if (g == 0) {
            v4f* dst = (v4f*)(lds_acc + wave * DD);
            dst[0 * 16 + sub] = a0; dst[1 * 16 + sub] = a1;
            dst[2 * 16 + sub] = a2; dst[3 * 16 + sub] = a3;
        }
        if (lane == 0) lds_sum[wave] = lsum;
        __syncthreads();
        float tot = lds_acc[0 * DD + tid] + lds_acc[1 * DD + tid] +
                    lds_acc[2 * DD + tid] + lds_acc[3 * DD + tid];
        ws[WS_P1ACC + (size_t)(b * SPLIT + s) * DD + tid] = tot;
        if (tid == 0)
            ws[WS_P1SUM + b * SPLIT + s] =
                lds_sum[0] + lds_sum[1] + lds_sum[2] + lds_sum[3];
    }

    // ---------------- phase S: sentiment (two additive heads) ----------------
    {
        const v4f* wsp = (const v4f*)w_ss;
        const v4f* wap = (const v4f*)w_sa;
        const v4f ws0 = wsp[0 * 16 + sub], ws1 = wsp[1 * 16 + sub],
                  ws2 = wsp[2 * 16 + sub], ws3 = wsp[3 * 16 + sub];
        const v4f wa0 = wap[0 * 16 + sub], wa1 = wap[1 * 16 + sub],
                  wa2 = wap[2 * 16 + sub], wa3 = wap[3 * 16 + sub];
        const float* base = smem_g + ((size_t)b * TT + t0w + g) * DD + sub * 4;
        const float* mrow = mask + (size_t)b * TT + t0w + g;
        v4f s0 = (v4f)(0.f), s1 = s0, s2 = s0, s3 = s0;
        v4f q0 = s0, q1 = s0, q2 = s0, q3 = s0;
        float lss = 0.f, lsa = 0.f;
        v4f v0 = ntload4(base + 0);
        v4f v1 = ntload4(base + 64);
        v4f v2 = ntload4(base + 128);
        v4f v3 = ntload4(base + 192);
        for (int r = 0; r < ROWS_PER_WAVE; r += 4) {
            const int rn = (r + 4 < ROWS_PER_WAVE) ? (r + 4) : r;
            const float* nb = base + (size_t)rn * DD;
            v4f n0 = ntload4(nb + 0);
            v4f n1 = ntload4(nb + 64);
            v4f n2 = ntload4(nb + 128);
            v4f n3 = ntload4(nb + 192);
            float m = mrow[r];
            float pds = (dot4v(v0, ws0) + dot4v(v1, ws1)) +
                        (dot4v(v2, ws2) + dot4v(v3, ws3));
            float pda = (dot4v(v0, wa0) + dot4v(v1, wa1)) +
                        (dot4v(v2, wa2) + dot4v(v3, wa3));
            float dss = red16(pds);
            float dsa = red16(pda);
            float ess = __expf(dss) * m;
            float esa = __expf(dsa) * m;
            lss += ess;
            lsa += esa;
            fma4v(s0, ess, v0); fma4v(s1, ess, v1);
            fma4v(s2, ess, v2); fma4v(s3, ess, v3);
            fma4v(q0, esa, v0); fma4v(q1, esa, v1);
            fma4v(q2, esa, v2); fma4v(q3, esa, v3);
            v0 = n0; v1 = n1; v2 = n2; v3 = n3;
        }
        lss = xmerge(lss);
        lsa = xmerge(lsa);
        merge4(s0); merge4(s1); merge4(s2); merge4(s3);
        merge4(q0); merge4(q1); merge4(q2); merge4(q3);
        __syncthreads();   // phase-A LDS reads fully done before reuse
        if (g == 0) {
            v4f* d1 = (v4f*)(lds_acc + wave * DD);
            d1[0 * 16 + sub] = s0; d1[1 * 16 + sub] = s1;
            d1[2 * 16 + sub] = s2; d1[3 * 16 + sub] = s3;
            v4f* d2 = (v4f*)(lds_acc + (WAVES + wave) * DD);
            d2[0 * 16 + sub] = q0; d2[1 * 16 + sub] = q1;
            d2[2 * 16 + sub] = q2; d2[3 * 16 + sub] = q3;
        }
        if (lane == 0) {
            lds_sum[wave] = lss;
            lds_sum[WAVES + wave] = lsa;
        }
        __syncthreads();
        float tot_ss = lds_acc[0 * DD + tid] + lds_acc[1 * DD + tid] +
                       lds_acc[2 * DD + tid] + lds_acc[3 * DD + tid];
        float tot_sa = lds_acc[(WAVES + 0) * DD + tid] + lds_acc[(WAVES + 1) * DD + tid] +
                       lds_acc[(WAVES + 2) * DD + tid] + lds_acc[(WAVES + 3) * DD + tid];
        ws[WS_P2ACC_SS + (size_t)(b * SPLIT + s) * DD + tid] = tot_ss;
        ws[WS_P2ACC_SA + (size_t)(b * SPLIT + s) * DD + tid] = tot_sa;
        if (tid == 0) {
            ws[WS_P2SUM_SS + b * SPLIT + s] =
                lds_sum[0] + lds_sum[1] + lds_sum[2] + lds_sum[3];
            ws[WS_P2SUM_SA + b * SPLIT + s] =
                lds_sum[4] + lds_sum[5] + lds_sum[6] + lds_sum[7];
        }
    }
}

// K_combine: grid (B, 2).  y=0: aspect_out = aspect + new_aspect.
// y=1: sentiment_out = 0.5*acc_ss/l_ss + 0.5*acc_sa/l_sa.
__global__ __launch_bounds__(DD) void combine_kernel(
    const float* __restrict__ aspect, const float* __restrict__ ws,
    float* __restrict__ out)
{
    const int b = blockIdx.x;
    const int d = threadIdx.x;
    if (blockIdx.y == 0) {
        float acc = 0.f, l = 0.f;
        #pragma unroll
        for (int s = 0; s < SPLIT; ++s)
            acc += ws[WS_P1ACC + (size_t)(b * SPLIT + s) * DD + d];
        #pragma unroll
        for (int s = 0; s < SPLIT; ++s)
            l += ws[WS_P1SUM + b * SPLIT + s];
        out[BB * DD + b * DD + d] = aspect[b * DD + d] + acc / l;
    } else {
        float ass = 0.f, asa = 0.f, lss = 0.f, lsa = 0.f;
        #pragma unroll
        for (int s = 0; s < SPLIT; ++s) {
            ass += ws[WS_P2ACC_SS + (size_t)(b * SPLIT + s) * DD + d];
            asa += ws[WS_P2ACC_SA + (size_t)(b * SPLIT + s) * DD + d];
        }
        #pragma unroll
        for (int s = 0; s < SPLIT; ++s) {
            lss += ws[WS_P2SUM_SS + b * SPLIT + s];
            lsa += ws[WS_P2SUM_SA + b * SPLIT + s];
        }
        out[b * DD + d] = 0.5f * (ass / lss) + 0.5f * (asa / lsa);
    }
}

extern "C" void kernel_launch(void* const* d_in, const int* in_sizes, int n_in,
                              void* d_out, int out_size, void* d_ws, size_t ws_size,
                              hipStream_t stream) {
    (void)in_sizes; (void)n_in; (void)out_size; (void)ws_size;
    // d_in order per setup_inputs():
    // 0 sentiment [B,D] (unused: query term is softmax-shift-invariant)
    // 1 aspect [B,D], 2 sentiment_memory [B,T,D], 3 aspect_memory [B,T,D],
    // 4 mask [B,T], 5 W_mul [D,D], 6 b_mul [1],
    // 7 w_ss [2D], 8 b_ss [1] (unused), 9 w_sa [2D], 10 b_sa [1] (unused)
    const float* aspect = (const float*)d_in[1];
    const float* smem   = (const float*)d_in[2];
    const float* amem   = (const float*)d_in[3];
    const float* mask   = (const float*)d_in[4];
    const float* W_mul  = (const float*)d_in[5];
    const float* b_mul  = (const float*)d_in[6];
    const float* w_ss   = (const float*)d_in[7];
    const float* w_sa   = (const float*)d_in[9];
    float* out = (float*)d_out;
    float* ws  = (float*)d_ws;

    mids_kernel<<<BB, DD, 0, stream>>>(aspect, W_mul, ws);
    pass_kernel<<<dim3(SPLIT, BB), 256, 0, stream>>>(
        smem, amem, mask, w_ss, w_sa, b_mul, ws);
    combine_kernel<<<dim3(BB, 2), DD, 0, stream>>>(aspect, ws, out);
}